// Round 1
// baseline (46.454 us; speedup 1.0000x reference)
//
#include <hip/hip_runtime.h>
#include <hip/hip_bf16.h>

// MeanAggregator: out[n,d] = sum_k mask[n,k]*feat[idx[n,k],d] / max(cnt,1), 0 if cnt==0
// features: [60000,128] f32, idx: [10000,64] i32, mask: [10000,64] i32 (0/1)

#define N_NEIGH 64
#define D_FEAT 128

__global__ __launch_bounds__(256) void mean_agg_kernel(
    const float* __restrict__ feat,
    const int* __restrict__ idx,
    const int* __restrict__ mask,
    float* __restrict__ out,
    int n_nodes)
{
    const int node = blockIdx.x;
    if (node >= n_nodes) return;

    __shared__ int   s_idx[N_NEIGH];
    __shared__ float s_m[N_NEIGH];
    __shared__ float4 s_part[8][32];
    __shared__ float s_cnt[8];

    const int tid = threadIdx.x;

    // Stage idx+mask for this node into LDS (threads 0..63 idx, 64..127 mask)
    if (tid < N_NEIGH) {
        s_idx[tid] = idx[(long)node * N_NEIGH + tid];
    } else if (tid < 2 * N_NEIGH) {
        int k = tid - N_NEIGH;
        s_m[k] = (mask[(long)node * N_NEIGH + k] != 0) ? 1.0f : 0.0f;
    }
    __syncthreads();

    const int d4 = tid & 31;   // which float4 of the 128-float row
    const int kg = tid >> 5;   // k-group 0..7, each handles 8 neighbors

    float4 acc = make_float4(0.f, 0.f, 0.f, 0.f);
    float cnt = 0.f;

    #pragma unroll
    for (int j = 0; j < 8; ++j) {
        const int k = kg * 8 + j;
        const float m = s_m[k];
        const long row = (long)s_idx[k] * D_FEAT;
        const float4 v = ((const float4*)(feat + row))[d4];
        acc.x += m * v.x;
        acc.y += m * v.y;
        acc.z += m * v.z;
        acc.w += m * v.w;
        cnt   += m;
    }

    s_part[kg][d4] = acc;
    if (d4 == 0) s_cnt[kg] = cnt;
    __syncthreads();

    if (tid < 32) {
        float4 t = make_float4(0.f, 0.f, 0.f, 0.f);
        float c = 0.f;
        #pragma unroll
        for (int g = 0; g < 8; ++g) {
            const float4 p = s_part[g][tid];
            t.x += p.x; t.y += p.y; t.z += p.z; t.w += p.w;
            c += s_cnt[g];
        }
        const float inv = (c > 0.f) ? (1.0f / c) : 0.0f;
        t.x *= inv; t.y *= inv; t.z *= inv; t.w *= inv;
        ((float4*)(out + (long)node * D_FEAT))[tid] = t;
    }
}

extern "C" void kernel_launch(void* const* d_in, const int* in_sizes, int n_in,
                              void* d_out, int out_size, void* d_ws, size_t ws_size,
                              hipStream_t stream) {
    const float* feat = (const float*)d_in[0];
    const int*   idx  = (const int*)d_in[1];
    const int*   mask = (const int*)d_in[2];
    float*       out  = (float*)d_out;

    const int n_nodes = in_sizes[1] / N_NEIGH;  // 10000

    mean_agg_kernel<<<n_nodes, 256, 0, stream>>>(feat, idx, mask, out, n_nodes);
}

// Round 2
// 34.308 us; speedup vs baseline: 1.3540x; 1.3540x over previous
//
#include <hip/hip_runtime.h>
#include <hip/hip_bf16.h>
#include <hip/hip_fp16.h>

// MeanAggregator: out[n,d] = sum_k mask[n,k]*feat[idx[n,k],d] / max(cnt,1), 0 if cnt==0
// features: [60000,128] f32, idx: [10000,64] i32, mask: [10000,64] i32 (0/1)
//
// Strategy: (1) convert feature table to fp16 in d_ws (halves scattered gather
// bytes, doubles effective L2 coverage), (2) gather with mask-skip (don't load
// rows whose mask is 0 — halves demand again). Accumulate in f32.

#define N_NEIGH 64
#define D_FEAT 128

__global__ __launch_bounds__(256) void convert_f32_to_f16(
    const float* __restrict__ feat,
    __half* __restrict__ feat16,
    int n_vec8)   // total elements / 8
{
    int i = blockIdx.x * blockDim.x + threadIdx.x;
    if (i >= n_vec8) return;
    const float4* src = (const float4*)feat;
    float4 a = src[2 * i];
    float4 b = src[2 * i + 1];
    float4 packed;
    __half2* p = (__half2*)&packed;
    p[0] = __floats2half2_rn(a.x, a.y);
    p[1] = __floats2half2_rn(a.z, a.w);
    p[2] = __floats2half2_rn(b.x, b.y);
    p[3] = __floats2half2_rn(b.z, b.w);
    ((float4*)feat16)[i] = packed;
}

__global__ __launch_bounds__(256) void mean_agg_f16(
    const __half* __restrict__ feat16,
    const int* __restrict__ idx,
    const int* __restrict__ mask,
    float* __restrict__ out,
    int n_nodes)
{
    const int node = blockIdx.x;
    if (node >= n_nodes) return;

    __shared__ int s_idx[N_NEIGH];
    __shared__ int s_m[N_NEIGH];
    __shared__ float4 s_part[8][32];
    __shared__ float s_cnt[8];

    const int tid = threadIdx.x;

    if (tid < N_NEIGH) {
        s_idx[tid] = idx[(long)node * N_NEIGH + tid];
    } else if (tid < 2 * N_NEIGH) {
        int k = tid - N_NEIGH;
        s_m[k] = mask[(long)node * N_NEIGH + k];
    }
    __syncthreads();

    const int d4 = tid & 31;   // which 4-feature chunk of the 128-float row
    const int kg = tid >> 5;   // k-group 0..7, each handles 8 neighbors

    float4 acc = make_float4(0.f, 0.f, 0.f, 0.f);
    float cnt = 0.f;

    #pragma unroll
    for (int j = 0; j < 8; ++j) {
        const int k = kg * 8 + j;
        if (s_m[k] != 0) {                      // mask-skip: no load if masked off
            const __half* row = feat16 + (long)s_idx[k] * D_FEAT;
            float2 r = ((const float2*)row)[d4];  // 8 B = 4 halves, coalesced 256 B/row
            const __half2* hv = (const __half2*)&r;
            float2 f01 = __half22float2(hv[0]);
            float2 f23 = __half22float2(hv[1]);
            acc.x += f01.x;
            acc.y += f01.y;
            acc.z += f23.x;
            acc.w += f23.y;
            cnt += 1.f;
        }
    }

    s_part[kg][d4] = acc;
    if (d4 == 0) s_cnt[kg] = cnt;
    __syncthreads();

    if (tid < 32) {
        float4 t = make_float4(0.f, 0.f, 0.f, 0.f);
        float c = 0.f;
        #pragma unroll
        for (int g = 0; g < 8; ++g) {
            const float4 p = s_part[g][tid];
            t.x += p.x; t.y += p.y; t.z += p.z; t.w += p.w;
            c += s_cnt[g];
        }
        const float inv = (c > 0.f) ? (1.0f / c) : 0.0f;
        t.x *= inv; t.y *= inv; t.z *= inv; t.w *= inv;
        ((float4*)(out + (long)node * D_FEAT))[tid] = t;
    }
}

// Fallback (ws too small): f32 gather with mask-skip only.
__global__ __launch_bounds__(256) void mean_agg_f32(
    const float* __restrict__ feat,
    const int* __restrict__ idx,
    const int* __restrict__ mask,
    float* __restrict__ out,
    int n_nodes)
{
    const int node = blockIdx.x;
    if (node >= n_nodes) return;

    __shared__ int s_idx[N_NEIGH];
    __shared__ int s_m[N_NEIGH];
    __shared__ float4 s_part[8][32];
    __shared__ float s_cnt[8];

    const int tid = threadIdx.x;

    if (tid < N_NEIGH) {
        s_idx[tid] = idx[(long)node * N_NEIGH + tid];
    } else if (tid < 2 * N_NEIGH) {
        int k = tid - N_NEIGH;
        s_m[k] = mask[(long)node * N_NEIGH + k];
    }
    __syncthreads();

    const int d4 = tid & 31;
    const int kg = tid >> 5;

    float4 acc = make_float4(0.f, 0.f, 0.f, 0.f);
    float cnt = 0.f;

    #pragma unroll
    for (int j = 0; j < 8; ++j) {
        const int k = kg * 8 + j;
        if (s_m[k] != 0) {
            const float4 v = ((const float4*)(feat + (long)s_idx[k] * D_FEAT))[d4];
            acc.x += v.x; acc.y += v.y; acc.z += v.z; acc.w += v.w;
            cnt += 1.f;
        }
    }

    s_part[kg][d4] = acc;
    if (d4 == 0) s_cnt[kg] = cnt;
    __syncthreads();

    if (tid < 32) {
        float4 t = make_float4(0.f, 0.f, 0.f, 0.f);
        float c = 0.f;
        #pragma unroll
        for (int g = 0; g < 8; ++g) {
            const float4 p = s_part[g][tid];
            t.x += p.x; t.y += p.y; t.z += p.z; t.w += p.w;
            c += s_cnt[g];
        }
        const float inv = (c > 0.f) ? (1.0f / c) : 0.0f;
        t.x *= inv; t.y *= inv; t.z *= inv; t.w *= inv;
        ((float4*)(out + (long)node * D_FEAT))[tid] = t;
    }
}

extern "C" void kernel_launch(void* const* d_in, const int* in_sizes, int n_in,
                              void* d_out, int out_size, void* d_ws, size_t ws_size,
                              hipStream_t stream) {
    const float* feat = (const float*)d_in[0];
    const int*   idx  = (const int*)d_in[1];
    const int*   mask = (const int*)d_in[2];
    float*       out  = (float*)d_out;

    const int n_nodes = in_sizes[1] / N_NEIGH;       // 10000
    const int n_feat_elems = in_sizes[0];            // 60000*128
    const size_t ws_needed = (size_t)n_feat_elems * sizeof(__half);

    if (ws_size >= ws_needed) {
        __half* feat16 = (__half*)d_ws;
        const int n_vec8 = n_feat_elems / 8;         // 960000
        convert_f32_to_f16<<<(n_vec8 + 255) / 256, 256, 0, stream>>>(feat, feat16, n_vec8);
        mean_agg_f16<<<n_nodes, 256, 0, stream>>>(feat16, idx, mask, out, n_nodes);
    } else {
        mean_agg_f32<<<n_nodes, 256, 0, stream>>>(feat, idx, mask, out, n_nodes);
    }
}

// Round 3
// 30.702 us; speedup vs baseline: 1.5131x; 1.1175x over previous
//
#include <hip/hip_runtime.h>
#include <hip/hip_bf16.h>
#include <hip/hip_fp16.h>

// MeanAggregator: out[n,d] = sum_k mask[n,k]*feat[idx[n,k],d] / max(cnt,1), 0 if cnt==0
// features: [60000,128] f32, idx: [10000,64] i32, mask: [10000,64] i32 (0/1)
//
// R3 strategy: gather is load-instruction/latency-bound (R1->R2 evidence), so:
//  - fp16 table in d_ws (256 B rows)
//  - ballot-compacted index list (no per-row mask branches)
//  - 16 lanes x 16 B per row -> 4 rows per wave-instruction (2x fewer instrs than R2)
//  - shfl_xor reduce + small LDS combine

#define N_NEIGH 64
#define D_FEAT 128

__global__ __launch_bounds__(256) void convert_f32_to_f16(
    const float* __restrict__ feat,
    __half* __restrict__ feat16,
    int n_vec8)   // total elements / 8
{
    int i = blockIdx.x * blockDim.x + threadIdx.x;
    if (i >= n_vec8) return;
    const float4* src = (const float4*)feat;
    float4 a = src[2 * i];
    float4 b = src[2 * i + 1];
    float4 packed;
    __half2* p = (__half2*)&packed;
    p[0] = __floats2half2_rn(a.x, a.y);
    p[1] = __floats2half2_rn(a.z, a.w);
    p[2] = __floats2half2_rn(b.x, b.y);
    p[3] = __floats2half2_rn(b.z, b.w);
    ((float4*)feat16)[i] = packed;
}

__global__ __launch_bounds__(256) void mean_agg_f16c(
    const __half* __restrict__ feat16,
    const int* __restrict__ idx,
    const int* __restrict__ mask,
    float* __restrict__ out,
    int n_nodes)
{
    const int node = blockIdx.x;
    if (node >= n_nodes) return;

    __shared__ int s_cidx[N_NEIGH];
    __shared__ int s_cnt;
    __shared__ float s_part[4][D_FEAT];

    const int tid = threadIdx.x;

    // Wave 0: load idx+mask, ballot-compact unmasked indices into s_cidx[0..cnt)
    if (tid < N_NEIGH) {
        const int i = idx[(long)node * N_NEIGH + tid];
        const int m = mask[(long)node * N_NEIGH + tid];
        const unsigned long long bal = __ballot(m != 0);
        const int pos = __popcll(bal & ((1ull << tid) - 1ull));
        if (m) s_cidx[pos] = i;
        if (tid == 0) s_cnt = (int)__popcll(bal);
    }
    __syncthreads();

    const int cnt = s_cnt;
    const int slot = tid >> 4;   // 0..15: which compacted row this thread helps load
    const int d8   = tid & 15;   // which 16B chunk (8 halves) of the 256B row

    float acc[8] = {0.f, 0.f, 0.f, 0.f, 0.f, 0.f, 0.f, 0.f};

    // Up to 64 compacted rows, 16 row-slots per sweep, 4 sweeps fully unrolled:
    // all loads issued up-front under exec-mask (max MLP, no branch-back).
    #pragma unroll
    for (int rr = 0; rr < 4; ++rr) {
        const int r = slot + rr * 16;
        if (r < cnt) {
            const __half* row = feat16 + (long)s_cidx[r] * D_FEAT;
            const float4 v = ((const float4*)row)[d8];
            const __half2* h = (const __half2*)&v;
            float2 f;
            f = __half22float2(h[0]); acc[0] += f.x; acc[1] += f.y;
            f = __half22float2(h[1]); acc[2] += f.x; acc[3] += f.y;
            f = __half22float2(h[2]); acc[4] += f.x; acc[5] += f.y;
            f = __half22float2(h[3]); acc[6] += f.x; acc[7] += f.y;
        }
    }

    // Reduce across the 4 slots within each wave (lanes differing in bits 4,5)
    #pragma unroll
    for (int j = 0; j < 8; ++j) {
        acc[j] += __shfl_xor(acc[j], 16);
        acc[j] += __shfl_xor(acc[j], 32);
    }

    // Lanes 0..15 of each wave write their 8-float partial (2x float4)
    const int wv = tid >> 6;
    if ((tid & 63) < 16) {
        float4* dst = (float4*)&s_part[wv][d8 * 8];
        dst[0] = make_float4(acc[0], acc[1], acc[2], acc[3]);
        dst[1] = make_float4(acc[4], acc[5], acc[6], acc[7]);
    }
    __syncthreads();

    // Final: 128 threads combine 4 wave-partials, scale, store (coalesced)
    if (tid < D_FEAT) {
        const float s = s_part[0][tid] + s_part[1][tid] + s_part[2][tid] + s_part[3][tid];
        const float inv = (cnt > 0) ? (1.0f / (float)cnt) : 0.0f;
        out[(long)node * D_FEAT + tid] = s * inv;
    }
}

// Fallback (ws too small): f32 gather with mask-skip only.
__global__ __launch_bounds__(256) void mean_agg_f32(
    const float* __restrict__ feat,
    const int* __restrict__ idx,
    const int* __restrict__ mask,
    float* __restrict__ out,
    int n_nodes)
{
    const int node = blockIdx.x;
    if (node >= n_nodes) return;

    __shared__ int s_idx[N_NEIGH];
    __shared__ int s_m[N_NEIGH];
    __shared__ float4 s_part[8][32];
    __shared__ float s_cnt[8];

    const int tid = threadIdx.x;

    if (tid < N_NEIGH) {
        s_idx[tid] = idx[(long)node * N_NEIGH + tid];
    } else if (tid < 2 * N_NEIGH) {
        int k = tid - N_NEIGH;
        s_m[k] = mask[(long)node * N_NEIGH + k];
    }
    __syncthreads();

    const int d4 = tid & 31;
    const int kg = tid >> 5;

    float4 acc = make_float4(0.f, 0.f, 0.f, 0.f);
    float cnt = 0.f;

    #pragma unroll
    for (int j = 0; j < 8; ++j) {
        const int k = kg * 8 + j;
        if (s_m[k] != 0) {
            const float4 v = ((const float4*)(feat + (long)s_idx[k] * D_FEAT))[d4];
            acc.x += v.x; acc.y += v.y; acc.z += v.z; acc.w += v.w;
            cnt += 1.f;
        }
    }

    s_part[kg][d4] = acc;
    if (d4 == 0) s_cnt[kg] = cnt;
    __syncthreads();

    if (tid < 32) {
        float4 t = make_float4(0.f, 0.f, 0.f, 0.f);
        float c = 0.f;
        #pragma unroll
        for (int g = 0; g < 8; ++g) {
            const float4 p = s_part[g][tid];
            t.x += p.x; t.y += p.y; t.z += p.z; t.w += p.w;
            c += s_cnt[g];
        }
        const float inv = (c > 0.f) ? (1.0f / c) : 0.0f;
        t.x *= inv; t.y *= inv; t.z *= inv; t.w *= inv;
        ((float4*)(out + (long)node * D_FEAT))[tid] = t;
    }
}

extern "C" void kernel_launch(void* const* d_in, const int* in_sizes, int n_in,
                              void* d_out, int out_size, void* d_ws, size_t ws_size,
                              hipStream_t stream) {
    const float* feat = (const float*)d_in[0];
    const int*   idx  = (const int*)d_in[1];
    const int*   mask = (const int*)d_in[2];
    float*       out  = (float*)d_out;

    const int n_nodes = in_sizes[1] / N_NEIGH;       // 10000
    const int n_feat_elems = in_sizes[0];            // 60000*128
    const size_t ws_needed = (size_t)n_feat_elems * sizeof(__half);

    if (ws_size >= ws_needed) {
        __half* feat16 = (__half*)d_ws;
        const int n_vec8 = n_feat_elems / 8;         // 960000
        convert_f32_to_f16<<<(n_vec8 + 255) / 256, 256, 0, stream>>>(feat, feat16, n_vec8);
        mean_agg_f16c<<<n_nodes, 256, 0, stream>>>(feat16, idx, mask, out, n_nodes);
    } else {
        mean_agg_f32<<<n_nodes, 256, 0, stream>>>(feat, idx, mask, out, n_nodes);
    }
}

// Round 4
// 29.313 us; speedup vs baseline: 1.5848x; 1.0474x over previous
//
#include <hip/hip_runtime.h>
#include <hip/hip_bf16.h>

// MeanAggregator: out[n,d] = sum_k mask[n,k]*feat[idx[n,k],d] / max(cnt,1), 0 if cnt==0
// features: [60000,128] f32, idx: [10000,64] i32, mask: [10000,64] i32 (0/1)
//
// R4: single-kernel f32-direct gather (no fp16 convert pass).
//  - ballot-compacted index list (no per-row mask branches)
//  - 32 lanes x 16 B per f32 row (512 B) -> 2 rows per wave-instruction
//  - 8 row-slots/sweep (256 thr), 8 sweeps fully unrolled, predicated loads
//  - shfl_xor(32) intra-wave reduce + 4-entry LDS combine
// This isolates the gather cost (dur_us == gather kernel) to discriminate
// byte-bound vs latency-bound regimes.

#define N_NEIGH 64
#define D_FEAT 128

__global__ __launch_bounds__(256) void mean_agg_f32c(
    const float* __restrict__ feat,
    const int* __restrict__ idx,
    const int* __restrict__ mask,
    float* __restrict__ out,
    int n_nodes)
{
    const int node = blockIdx.x;

    __shared__ int s_cidx[N_NEIGH];
    __shared__ int s_cnt;
    __shared__ float4 s_part[4][32];

    const int tid = threadIdx.x;

    // Wave 0: load idx+mask, ballot-compact unmasked indices into s_cidx[0..cnt)
    if (tid < 64) {
        const int i = idx[(long)node * N_NEIGH + tid];
        const int m = mask[(long)node * N_NEIGH + tid];
        const unsigned long long bal = __ballot(m != 0);
        const int pos = __popcll(bal & ((1ull << tid) - 1ull));
        if (m) s_cidx[pos] = i;
        if (tid == 0) s_cnt = (int)__popcll(bal);
    }
    __syncthreads();

    const int cnt = s_cnt;
    const int slot = tid >> 5;   // 0..7: which compacted row this thread helps load
    const int d4   = tid & 31;   // which 16B chunk of the 512B f32 row

    float4 acc = make_float4(0.f, 0.f, 0.f, 0.f);

    // Up to 64 compacted rows, 8 row-slots per sweep, 8 sweeps fully unrolled:
    // all loads issued up-front under exec-mask (max MLP, no branch-back).
    #pragma unroll
    for (int rr = 0; rr < 8; ++rr) {
        const int r = slot + rr * 8;
        if (r < cnt) {
            const float4 v = ((const float4*)(feat + (long)s_cidx[r] * D_FEAT))[d4];
            acc.x += v.x; acc.y += v.y; acc.z += v.z; acc.w += v.w;
        }
    }

    // Lanes differing in bit 5 hold the two slots of this wave: combine.
    acc.x += __shfl_xor(acc.x, 32);
    acc.y += __shfl_xor(acc.y, 32);
    acc.z += __shfl_xor(acc.z, 32);
    acc.w += __shfl_xor(acc.w, 32);

    // Lanes 0..31 of each wave write their float4 partial
    const int wv = tid >> 6;
    if ((tid & 63) < 32) {
        s_part[wv][d4] = acc;
    }
    __syncthreads();

    // Final: 32 threads combine 4 wave-partials, scale, store (512B coalesced)
    if (tid < 32) {
        const float4 p0 = s_part[0][tid];
        const float4 p1 = s_part[1][tid];
        const float4 p2 = s_part[2][tid];
        const float4 p3 = s_part[3][tid];
        float4 t;
        t.x = (p0.x + p1.x) + (p2.x + p3.x);
        t.y = (p0.y + p1.y) + (p2.y + p3.y);
        t.z = (p0.z + p1.z) + (p2.z + p3.z);
        t.w = (p0.w + p1.w) + (p2.w + p3.w);
        const float inv = (cnt > 0) ? (1.0f / (float)cnt) : 0.0f;
        t.x *= inv; t.y *= inv; t.z *= inv; t.w *= inv;
        ((float4*)(out + (long)node * D_FEAT))[tid] = t;
    }
}

extern "C" void kernel_launch(void* const* d_in, const int* in_sizes, int n_in,
                              void* d_out, int out_size, void* d_ws, size_t ws_size,
                              hipStream_t stream) {
    const float* feat = (const float*)d_in[0];
    const int*   idx  = (const int*)d_in[1];
    const int*   mask = (const int*)d_in[2];
    float*       out  = (float*)d_out;

    const int n_nodes = in_sizes[1] / N_NEIGH;       // 10000

    mean_agg_f32c<<<n_nodes, 256, 0, stream>>>(feat, idx, mask, out, n_nodes);
}